// Round 3
// baseline (98.493 us; speedup 1.0000x reference)
//
#include <hip/hip_runtime.h>
#include <math.h>

// KAN layer forward, MI355X (gfx950).
// Shapes: batch=2048, n_in=64, n_out=64, n=4096, 10 knots/row (all rows equal),
// 6 cubic B-spline basis funcs per x (K=3). Outputs (both FLOAT32, concatenated
// flat in d_out): y (2048,64) then spl_reg (64,64). No workspace used.

#define BATCHN 2048
#define NI     64
#define NO     64
#define NTOTAL 4096

// Evaluate the 6 order-3 B-spline bases + silu for one x value.
// tt: 10 knots; invK[m] = 1/(tt[m+K]-tt[m]).
__device__ __forceinline__ void eval_basis6(float xv,
                                            const float* tt,
                                            const float* inv1,
                                            const float* inv2,
                                            const float* inv3,
                                            float* bout, float* silu)
{
    float c[10], d[10];
#pragma unroll
    for (int m = 0; m < 10; ++m) {
        c[m] = (xv >= tt[m]) ? 1.0f : 0.0f;
        d[m] = xv - tt[m];
    }
    float b[9], w[9];
#pragma unroll
    for (int m = 0; m < 9; ++m) b[m] = c[m] - c[m + 1];   // degree-0 indicator
#pragma unroll
    for (int m = 0; m < 9; ++m) w[m] = b[m] * inv1[m];
#pragma unroll
    for (int m = 0; m < 8; ++m) b[m] = d[m] * w[m] - d[m + 2] * w[m + 1];
#pragma unroll
    for (int m = 0; m < 8; ++m) w[m] = b[m] * inv2[m];
#pragma unroll
    for (int m = 0; m < 7; ++m) b[m] = d[m] * w[m] - d[m + 3] * w[m + 1];
#pragma unroll
    for (int m = 0; m < 7; ++m) w[m] = b[m] * inv3[m];
#pragma unroll
    for (int m = 0; m < 6; ++m) bout[m] = d[m] * w[m] - d[m + 4] * w[m + 1];
    *silu = xv / (1.0f + expf(-xv));
}

// Kernel 1: y[b,o] = (1/64) * sum_i ( c_spl[o*64+i]*spl(b,o*64+i) + c_res[o*64+i]*silu(x[b,i]) )
// Grid: 256 blocks (8 batches each) x 256 threads.
__global__ __launch_bounds__(256) void kan_y(
    const float* __restrict__ x, const float* __restrict__ cb,
    const float* __restrict__ c_spl, const float* __restrict__ c_res,
    const float* __restrict__ grid, float* __restrict__ y)
{
    __shared__ float sB[7][512];     // 6 basis + silu for p = bb*64 + i
    __shared__ float sP[8 * 256];    // per-(bb, o, quarter) partials

    const int t = threadIdx.x;
    const int bbase = blockIdx.x * 8;

    float tt[10];
#pragma unroll
    for (int m = 0; m < 10; ++m) tt[m] = grid[m];
    float inv1[9], inv2[8], inv3[7];
#pragma unroll
    for (int m = 0; m < 9; ++m) inv1[m] = 1.0f / (tt[m + 1] - tt[m]);
#pragma unroll
    for (int m = 0; m < 8; ++m) inv2[m] = 1.0f / (tt[m + 2] - tt[m]);
#pragma unroll
    for (int m = 0; m < 7; ++m) inv3[m] = 1.0f / (tt[m + 3] - tt[m]);

    // Phase 1: 512 basis evals -> LDS (coalesced x reads)
#pragma unroll
    for (int pp = 0; pp < 2; ++pp) {
        const int p = t + pp * 256;            // p = bb*64 + i
        const float xv = x[bbase * NI + p];
        float bo[6], sl;
        eval_basis6(xv, tt, inv1, inv2, inv3, bo, &sl);
#pragma unroll
        for (int m = 0; m < 6; ++m) sB[m][p] = bo[m];
        sB[6][p] = sl;
    }
    __syncthreads();

    // Phase 2: thread (o = t>>2, q = t&3) sums 16 i's for all 8 batches
    const int o = t >> 2;
    const int q = t & 3;
    float acc[8];
#pragma unroll
    for (int bb = 0; bb < 8; ++bb) acc[bb] = 0.0f;

    for (int ii = 0; ii < 16; ++ii) {
        const int i = q * 16 + ii;
        const int j = o * NI + i;
        const float c0 = cb[j * 6 + 0];
        const float c1 = cb[j * 6 + 1];
        const float c2 = cb[j * 6 + 2];
        const float c3 = cb[j * 6 + 3];
        const float c4 = cb[j * 6 + 4];
        const float c5 = cb[j * 6 + 5];
        const float cs = c_spl[j];
        const float cr = c_res[j];
#pragma unroll
        for (int bb = 0; bb < 8; ++bb) {
            const int p = bb * 64 + i;
            float s = c0 * sB[0][p];
            s = fmaf(c1, sB[1][p], s);
            s = fmaf(c2, sB[2][p], s);
            s = fmaf(c3, sB[3][p], s);
            s = fmaf(c4, sB[4][p], s);
            s = fmaf(c5, sB[5][p], s);
            acc[bb] += fmaf(cs, s, cr * sB[6][p]);
        }
    }
#pragma unroll
    for (int bb = 0; bb < 8; ++bb) sP[bb * 256 + t] = acc[bb];
    __syncthreads();

    // Reduce the 4 quarters per (bb, o) and store y (coalesced f32 stores)
#pragma unroll
    for (int pp = 0; pp < 2; ++pp) {
        const int r = t + pp * 256;            // r = bb*64 + o
        const int bb = r >> 6;
        const int oo = r & 63;
        const float s = sP[bb * 256 + oo * 4 + 0] + sP[bb * 256 + oo * 4 + 1]
                      + sP[bb * 256 + oo * 4 + 2] + sP[bb * 256 + oo * 4 + 3];
        y[(bbase + bb) * NO + oo] = s * (1.0f / 64.0f);
    }
}

// Kernel 2: spl_reg[o,i] = (1/2048) * sum_b |spl(b, o*64+i)| / (t9 - t0 + 1e-5)
// Grid: 64 blocks (one per i) x 256 threads. Recomputes basis; no workspace.
__global__ __launch_bounds__(256) void kan_reg(
    const float* __restrict__ x, const float* __restrict__ cb,
    const float* __restrict__ grid, float* __restrict__ outreg)
{
    __shared__ float sB2[6][256];   // basis for 256 batches of column i
    __shared__ float sR[256];

    const int t = threadIdx.x;
    const int i = blockIdx.x;       // 0..63

    float tt[10];
#pragma unroll
    for (int m = 0; m < 10; ++m) tt[m] = grid[m];
    float inv1[9], inv2[8], inv3[7];
#pragma unroll
    for (int m = 0; m < 9; ++m) inv1[m] = 1.0f / (tt[m + 1] - tt[m]);
#pragma unroll
    for (int m = 0; m < 8; ++m) inv2[m] = 1.0f / (tt[m + 2] - tt[m]);
#pragma unroll
    for (int m = 0; m < 7; ++m) inv3[m] = 1.0f / (tt[m + 3] - tt[m]);

    const int o = t >> 2;
    const int q = t & 3;
    const int j = o * NI + i;
    const float c0 = cb[j * 6 + 0];
    const float c1 = cb[j * 6 + 1];
    const float c2 = cb[j * 6 + 2];
    const float c3 = cb[j * 6 + 3];
    const float c4 = cb[j * 6 + 4];
    const float c5 = cb[j * 6 + 5];

    float acc = 0.0f;
    for (int tile = 0; tile < 8; ++tile) {
        const float xv = x[(tile * 256 + t) * NI + i];
        float bo[6], sl;
        eval_basis6(xv, tt, inv1, inv2, inv3, bo, &sl);
        __syncthreads();            // previous tile fully consumed
#pragma unroll
        for (int m = 0; m < 6; ++m) sB2[m][t] = bo[m];
        __syncthreads();
        // each (o,q) thread sums its quarter of the 256 staged batches,
        // rotated by q*8 to spread LDS banks
        for (int bi = 0; bi < 64; ++bi) {
            const int b = q * 64 + ((bi + q * 8) & 63);
            float s = c0 * sB2[0][b];
            s = fmaf(c1, sB2[1][b], s);
            s = fmaf(c2, sB2[2][b], s);
            s = fmaf(c3, sB2[3][b], s);
            s = fmaf(c4, sB2[4][b], s);
            s = fmaf(c5, sB2[5][b], s);
            acc += fabsf(s);
        }
    }
    sR[t] = acc;
    __syncthreads();
    if (t < 64) {
        const int oo = t;
        const float s = sR[oo * 4 + 0] + sR[oo * 4 + 1] + sR[oo * 4 + 2] + sR[oo * 4 + 3];
        const int jj = oo * NI + i;
        const float norm = grid[jj * 10 + 9] - grid[jj * 10] + 1e-5f;
        outreg[jj] = (s * (1.0f / (float)BATCHN)) / norm;
    }
}

extern "C" void kernel_launch(void* const* d_in, const int* in_sizes, int n_in,
                              void* d_out, int out_size, void* d_ws, size_t ws_size,
                              hipStream_t stream) {
    (void)in_sizes; (void)n_in; (void)d_ws; (void)ws_size; (void)out_size;
    const float* x    = (const float*)d_in[0];
    const float* cb   = (const float*)d_in[1];
    const float* cspl = (const float*)d_in[2];
    const float* cres = (const float*)d_in[3];
    const float* grid = (const float*)d_in[4];
    float* y      = (float*)d_out;
    float* outreg = y + BATCHN * NO;       // outputs concatenated: y then spl_reg

    kan_y<<<BATCHN / 8, 256, 0, stream>>>(x, cb, cspl, cres, grid, y);
    kan_reg<<<NI, 256, 0, stream>>>(x, cb, grid, outreg);
}

// Round 4
// 75.638 us; speedup vs baseline: 1.3022x; 1.3022x over previous
//
#include <hip/hip_runtime.h>
#include <math.h>

// KAN layer forward, MI355X (gfx950).
// batch=2048, n_in=64, n_out=64, n=4096, 10 knots (all rows identical), K=3.
// Outputs (FLOAT32, concat in d_out): y (2048,64) then spl_reg (64,64).
// Fused design: main kernel computes y AND per-chunk |spl| partials (-> d_ws),
// small reduce kernel finishes spl_reg. Fallback (tiny ws): round-3 kan_reg.

#define BATCHN 2048
#define NI     64
#define NO     64
#define NTOTAL 4096
#define BB     8                    // batches per chunk
#define NCHUNK (BATCHN / BB)        // 256
#define TPB    256

// 6 cubic B-spline bases + silu for one x (verified in round 3).
__device__ __forceinline__ void eval_basis6(float xv,
                                            const float* tt,
                                            const float* inv1,
                                            const float* inv2,
                                            const float* inv3,
                                            float* bout, float* silu)
{
    float c[10], d[10];
#pragma unroll
    for (int m = 0; m < 10; ++m) {
        c[m] = (xv >= tt[m]) ? 1.0f : 0.0f;
        d[m] = xv - tt[m];
    }
    float b[9], w[9];
#pragma unroll
    for (int m = 0; m < 9; ++m) b[m] = c[m] - c[m + 1];
#pragma unroll
    for (int m = 0; m < 9; ++m) w[m] = b[m] * inv1[m];
#pragma unroll
    for (int m = 0; m < 8; ++m) b[m] = d[m] * w[m] - d[m + 2] * w[m + 1];
#pragma unroll
    for (int m = 0; m < 8; ++m) w[m] = b[m] * inv2[m];
#pragma unroll
    for (int m = 0; m < 7; ++m) b[m] = d[m] * w[m] - d[m + 3] * w[m + 1];
#pragma unroll
    for (int m = 0; m < 7; ++m) w[m] = b[m] * inv3[m];
#pragma unroll
    for (int m = 0; m < 6; ++m) bout[m] = d[m] * w[m] - d[m + 4] * w[m + 1];
    *silu = xv / (1.0f + expf(-xv));
}

// Main kernel: grid = 512 = 256 batch-chunks x 2 output-halves.
// Thread: i = lane (fixed), basis for 8 batches in registers; j-loop covers
// this half's 2048 (o,i) cells. If WRITE_PART, also emits
// regpart[chunk][j] = sum_bb |spl| (coalesced, no atomics).
__global__ __launch_bounds__(TPB) void kan_main(
    const float* __restrict__ x, const float* __restrict__ cb,
    const float* __restrict__ c_spl, const float* __restrict__ c_res,
    const float* __restrict__ grid, float* __restrict__ y,
    float* __restrict__ regpart, int write_part)
{
    __shared__ float sB[7][512];   // 6 basis + silu, SoA
    const int t    = threadIdx.x;
    const int lane = t & 63;
    const int wv   = t >> 6;
    const int bchunk = blockIdx.x >> 1;
    const int half   = blockIdx.x & 1;
    const int bbase  = bchunk * BB;

    float tt[10];
#pragma unroll
    for (int m = 0; m < 10; ++m) tt[m] = grid[m];
    float inv1[9], inv2[8], inv3[7];
#pragma unroll
    for (int m = 0; m < 9; ++m) inv1[m] = 1.0f / (tt[m + 1] - tt[m]);
#pragma unroll
    for (int m = 0; m < 8; ++m) inv2[m] = 1.0f / (tt[m + 2] - tt[m]);
#pragma unroll
    for (int m = 0; m < 7; ++m) inv3[m] = 1.0f / (tt[m + 3] - tt[m]);

    // Phase 1: 512 basis evals (2/thread) -> LDS, coalesced x reads
#pragma unroll
    for (int pp = 0; pp < 2; ++pp) {
        const int p = t + pp * TPB;            // p = bb*64 + i
        const float xv = x[bbase * NI + p];
        float bo[6], sl;
        eval_basis6(xv, tt, inv1, inv2, inv3, bo, &sl);
#pragma unroll
        for (int m = 0; m < 6; ++m) sB[m][p] = bo[m];
        sB[6][p] = sl;
    }
    __syncthreads();

    // Phase 2: my (i=lane, bb=0..7) basis -> registers, once
    float B0[8], B1[8], B2[8], B3[8], B4[8], B5[8], SL[8];
#pragma unroll
    for (int bb = 0; bb < 8; ++bb) {
        const int p = bb * 64 + lane;
        B0[bb] = sB[0][p]; B1[bb] = sB[1][p]; B2[bb] = sB[2][p];
        B3[bb] = sB[3][p]; B4[bb] = sB[4][p]; B5[bb] = sB[5][p];
        SL[bb] = sB[6][p];
    }

    const bool p0 = (lane & 1), p1 = (lane & 2), p2 = (lane & 4);
    const int jj0 = half * 8;
#pragma unroll
    for (int jj = jj0; jj < jj0 + 8; ++jj) {
        const int j = jj * TPB + t;           // o = j>>6 (wave-uniform), i = lane
        const float* cbp = cb + j * 6;        // 24B stride, 8B aligned
        const float2 c01 = *(const float2*)(cbp);
        const float2 c23 = *(const float2*)(cbp + 2);
        const float2 c45 = *(const float2*)(cbp + 4);
        const float cs = c_spl[j];
        const float cr = c_res[j];

        float v[8];
        float rabs = 0.0f;
#pragma unroll
        for (int bb = 0; bb < 8; ++bb) {
            float s = c01.x * B0[bb];
            s = fmaf(c01.y, B1[bb], s);
            s = fmaf(c23.x, B2[bb], s);
            s = fmaf(c23.y, B3[bb], s);
            s = fmaf(c45.x, B4[bb], s);
            s = fmaf(c45.y, B5[bb], s);
            rabs += fabsf(s);
            v[bb] = fmaf(cs, s, cr * SL[bb]);
        }
        if (write_part) regpart[bchunk * NTOTAL + j] = rabs;

        // packed butterfly: 8 batch-sums over 64 lanes (i) in 10 shuffles.
        // After the 3 pack steps, v[0] on lane L holds bb =
        // 4*(L&1) + 2*((L>>1)&1) + ((L>>2)&1), summed over 8-lane groups.
#pragma unroll
        for (int r = 0; r < 4; ++r) {
            float send = p0 ? v[r] : v[r + 4];
            float recv = __shfl_xor(send, 1, 64);
            float keep = p0 ? v[r + 4] : v[r];
            v[r] = keep + recv;
        }
#pragma unroll
        for (int r = 0; r < 2; ++r) {
            float send = p1 ? v[r] : v[r + 2];
            float recv = __shfl_xor(send, 2, 64);
            float keep = p1 ? v[r + 2] : v[r];
            v[r] = keep + recv;
        }
        {
            float send = p2 ? v[0] : v[1];
            float recv = __shfl_xor(send, 4, 64);
            float keep = p2 ? v[1] : v[0];
            v[0] = keep + recv;
        }
        v[0] += __shfl_xor(v[0], 8, 64);
        v[0] += __shfl_xor(v[0], 16, 64);
        v[0] += __shfl_xor(v[0], 32, 64);
        if (lane < 8) {
            const int bbL = ((lane & 1) << 2) | (lane & 2) | ((lane >> 2) & 1);
            const int o = jj * 4 + wv;
            y[(bbase + bbL) * NO + o] = v[0] * (1.0f / 64.0f);
        }
    }
}

// Reduce: spl_reg[j] = (sum_chunk part[chunk][j]) / 2048 / (t9 - t0 + 1e-5)
__global__ __launch_bounds__(TPB) void kan_reduce(
    const float* __restrict__ regpart, const float* __restrict__ grid,
    float* __restrict__ outreg)
{
    __shared__ float sR[4][64];
    const int t = threadIdx.x;
    const int qo = t & 63, gs = t >> 6;
    const int q = blockIdx.x * 64 + qo;
    float s = 0.0f;
#pragma unroll 8
    for (int g = gs * 64; g < gs * 64 + 64; ++g) s += regpart[g * NTOTAL + q];
    sR[gs][qo] = s;
    __syncthreads();
    if (t < 64) {
        const float tot = sR[0][qo] + sR[1][qo] + sR[2][qo] + sR[3][qo];
        const float norm = grid[q * 10 + 9] - grid[q * 10] + 1e-5f;
        outreg[q] = (tot * (1.0f / (float)BATCHN)) / norm;
    }
}

// Fallback (ws too small): round-3 standalone spl_reg kernel (known-good).
__global__ __launch_bounds__(TPB) void kan_reg_standalone(
    const float* __restrict__ x, const float* __restrict__ cb,
    const float* __restrict__ grid, float* __restrict__ outreg)
{
    __shared__ float sB2[6][256];
    __shared__ float sR[256];
    const int t = threadIdx.x;
    const int i = blockIdx.x;

    float tt[10];
#pragma unroll
    for (int m = 0; m < 10; ++m) tt[m] = grid[m];
    float inv1[9], inv2[8], inv3[7];
#pragma unroll
    for (int m = 0; m < 9; ++m) inv1[m] = 1.0f / (tt[m + 1] - tt[m]);
#pragma unroll
    for (int m = 0; m < 8; ++m) inv2[m] = 1.0f / (tt[m + 2] - tt[m]);
#pragma unroll
    for (int m = 0; m < 7; ++m) inv3[m] = 1.0f / (tt[m + 3] - tt[m]);

    const int o = t >> 2;
    const int q = t & 3;
    const int j = o * NI + i;
    const float c0 = cb[j * 6 + 0], c1 = cb[j * 6 + 1], c2 = cb[j * 6 + 2];
    const float c3 = cb[j * 6 + 3], c4 = cb[j * 6 + 4], c5 = cb[j * 6 + 5];

    float acc = 0.0f;
    for (int tile = 0; tile < 8; ++tile) {
        const float xv = x[(tile * 256 + t) * NI + i];
        float bo[6], sl;
        eval_basis6(xv, tt, inv1, inv2, inv3, bo, &sl);
        __syncthreads();
#pragma unroll
        for (int m = 0; m < 6; ++m) sB2[m][t] = bo[m];
        __syncthreads();
        for (int bi = 0; bi < 64; ++bi) {
            const int b = q * 64 + ((bi + q * 8) & 63);
            float s = c0 * sB2[0][b];
            s = fmaf(c1, sB2[1][b], s);
            s = fmaf(c2, sB2[2][b], s);
            s = fmaf(c3, sB2[3][b], s);
            s = fmaf(c4, sB2[4][b], s);
            s = fmaf(c5, sB2[5][b], s);
            acc += fabsf(s);
        }
    }
    sR[t] = acc;
    __syncthreads();
    if (t < 64) {
        const float s = sR[t * 4 + 0] + sR[t * 4 + 1] + sR[t * 4 + 2] + sR[t * 4 + 3];
        const int jj = t * NI + i;
        const float norm = grid[jj * 10 + 9] - grid[jj * 10] + 1e-5f;
        outreg[jj] = (s * (1.0f / (float)BATCHN)) / norm;
    }
}

extern "C" void kernel_launch(void* const* d_in, const int* in_sizes, int n_in,
                              void* d_out, int out_size, void* d_ws, size_t ws_size,
                              hipStream_t stream) {
    (void)in_sizes; (void)n_in; (void)out_size;
    const float* x    = (const float*)d_in[0];
    const float* cb   = (const float*)d_in[1];
    const float* cspl = (const float*)d_in[2];
    const float* cres = (const float*)d_in[3];
    const float* grid = (const float*)d_in[4];
    float* y      = (float*)d_out;
    float* outreg = y + BATCHN * NO;

    const size_t needed = (size_t)NCHUNK * NTOTAL * sizeof(float);   // 4 MiB
    if (ws_size >= needed) {
        float* part = (float*)d_ws;
        kan_main<<<NCHUNK * 2, TPB, 0, stream>>>(x, cb, cspl, cres, grid, y, part, 1);
        kan_reduce<<<NTOTAL / 64, TPB, 0, stream>>>(part, grid, outreg);
    } else {
        kan_main<<<NCHUNK * 2, TPB, 0, stream>>>(x, cb, cspl, cres, grid, y,
                                                 (float*)d_ws, 0);
        kan_reg_standalone<<<NI, TPB, 0, stream>>>(x, cb, grid, outreg);
    }
}

// Round 6
// 73.943 us; speedup vs baseline: 1.3320x; 1.0229x over previous
//
#include <hip/hip_runtime.h>
#include <math.h>

// KAN layer forward, MI355X (gfx950).
// batch=2048, n_in=64, n_out=64, n=4096, 10 knots (all rows identical), K=3.
// Outputs (FLOAT32, concat in d_out): y (2048,64) then spl_reg (64,64).
// Main kernel: 256 blocks x 512 threads; block = 8-batch chunk, covers ALL
// 4096 j-cells (basis evaluated once per chunk). Thread: i = lane fixed,
// basis for 8 batches in registers (56 regs); y reduced over lanes with a
// 10-shuffle packed butterfly; |spl| chunk-partials -> d_ws, tiny reduce
// kernel finishes spl_reg.
// (Round 6 = round 5 resubmitted verbatim: round 5 hit a container-
//  acquisition infrastructure failure, the kernel never ran.)

#define BATCHN 2048
#define NI     64
#define NO     64
#define NTOTAL 4096
#define BB     8                    // batches per chunk
#define NCHUNK (BATCHN / BB)        // 256
#define TPB    512

// 6 cubic B-spline bases + silu for one x (verified round 3/4).
__device__ __forceinline__ void eval_basis6(float xv,
                                            const float* tt,
                                            const float* inv1,
                                            const float* inv2,
                                            const float* inv3,
                                            float* bout, float* silu)
{
    float c[10], d[10];
#pragma unroll
    for (int m = 0; m < 10; ++m) {
        c[m] = (xv >= tt[m]) ? 1.0f : 0.0f;
        d[m] = xv - tt[m];
    }
    float b[9], w[9];
#pragma unroll
    for (int m = 0; m < 9; ++m) b[m] = c[m] - c[m + 1];
#pragma unroll
    for (int m = 0; m < 9; ++m) w[m] = b[m] * inv1[m];
#pragma unroll
    for (int m = 0; m < 8; ++m) b[m] = d[m] * w[m] - d[m + 2] * w[m + 1];
#pragma unroll
    for (int m = 0; m < 8; ++m) w[m] = b[m] * inv2[m];
#pragma unroll
    for (int m = 0; m < 7; ++m) b[m] = d[m] * w[m] - d[m + 3] * w[m + 1];
#pragma unroll
    for (int m = 0; m < 7; ++m) w[m] = b[m] * inv3[m];
#pragma unroll
    for (int m = 0; m < 6; ++m) bout[m] = d[m] * w[m] - d[m + 4] * w[m + 1];
    *silu = xv / (1.0f + expf(-xv));
}

__global__ __launch_bounds__(TPB, 2) void kan_main(
    const float* __restrict__ x, const float* __restrict__ cb,
    const float* __restrict__ c_spl, const float* __restrict__ c_res,
    const float* __restrict__ grid, float* __restrict__ y,
    float* __restrict__ regpart, int write_part)
{
    __shared__ float sB[7][512];   // 6 basis + silu, SoA (2-way bank alias = free)
    const int t    = threadIdx.x;          // 0..511
    const int lane = t & 63;               // = i
    const int wv   = t >> 6;               // 0..7
    const int bchunk = blockIdx.x;         // 0..255
    const int bbase  = bchunk * BB;

    float tt[10];
#pragma unroll
    for (int m = 0; m < 10; ++m) tt[m] = grid[m];
    float inv1[9], inv2[8], inv3[7];
#pragma unroll
    for (int m = 0; m < 9; ++m) inv1[m] = 1.0f / (tt[m + 1] - tt[m]);
#pragma unroll
    for (int m = 0; m < 8; ++m) inv2[m] = 1.0f / (tt[m + 2] - tt[m]);
#pragma unroll
    for (int m = 0; m < 7; ++m) inv3[m] = 1.0f / (tt[m + 3] - tt[m]);

    // Phase 1: 512 basis evals, ONE per thread (was 2x redundant across
    // sibling half-blocks in round 4). Coalesced x reads.
    {
        const float xv = x[bbase * NI + t];      // t = bb*64 + i
        float bo[6], sl;
        eval_basis6(xv, tt, inv1, inv2, inv3, bo, &sl);
#pragma unroll
        for (int m = 0; m < 6; ++m) sB[m][t] = bo[m];
        sB[6][t] = sl;
    }
    __syncthreads();

    // Phase 2: my (i=lane, bb=0..7) basis -> 56 registers, once
    float B0[8], B1[8], B2[8], B3[8], B4[8], B5[8], SL[8];
#pragma unroll
    for (int bb = 0; bb < 8; ++bb) {
        const int p = bb * 64 + lane;
        B0[bb] = sB[0][p]; B1[bb] = sB[1][p]; B2[bb] = sB[2][p];
        B3[bb] = sB[3][p]; B4[bb] = sB[4][p]; B5[bb] = sB[5][p];
        SL[bb] = sB[6][p];
    }

    const bool p0 = (lane & 1), p1 = (lane & 2), p2 = (lane & 4);
#pragma unroll
    for (int jj = 0; jj < 8; ++jj) {
        const int j = jj * TPB + t;           // o = j>>6 = jj*8 + wv, i = lane
        const float* cbp = cb + j * 6;        // 24B stride, 8B aligned
        const float2 c01 = *(const float2*)(cbp);
        const float2 c23 = *(const float2*)(cbp + 2);
        const float2 c45 = *(const float2*)(cbp + 4);
        const float cs = c_spl[j];
        const float cr = c_res[j];

        float v[8];
        float rabs = 0.0f;
#pragma unroll
        for (int bb = 0; bb < 8; ++bb) {
            float s = c01.x * B0[bb];
            s = fmaf(c01.y, B1[bb], s);
            s = fmaf(c23.x, B2[bb], s);
            s = fmaf(c23.y, B3[bb], s);
            s = fmaf(c45.x, B4[bb], s);
            s = fmaf(c45.y, B5[bb], s);
            rabs += fabsf(s);
            v[bb] = fmaf(cs, s, cr * SL[bb]);
        }
        if (write_part) regpart[bchunk * NTOTAL + j] = rabs;  // coalesced

        // packed butterfly: 8 batch-sums over 64 lanes (i) in 10 shuffles.
        // After the 3 pack steps, v[0] on lane L holds batch index
        // bbL = 4*(L&1) + 2*((L>>1)&1) + ((L>>2)&1), summed per 8-lane group.
#pragma unroll
        for (int r = 0; r < 4; ++r) {
            float send = p0 ? v[r] : v[r + 4];
            float recv = __shfl_xor(send, 1, 64);
            float keep = p0 ? v[r + 4] : v[r];
            v[r] = keep + recv;
        }
#pragma unroll
        for (int r = 0; r < 2; ++r) {
            float send = p1 ? v[r] : v[r + 2];
            float recv = __shfl_xor(send, 2, 64);
            float keep = p1 ? v[r + 2] : v[r];
            v[r] = keep + recv;
        }
        {
            float send = p2 ? v[0] : v[1];
            float recv = __shfl_xor(send, 4, 64);
            float keep = p2 ? v[1] : v[0];
            v[0] = keep + recv;
        }
        v[0] += __shfl_xor(v[0], 8, 64);
        v[0] += __shfl_xor(v[0], 16, 64);
        v[0] += __shfl_xor(v[0], 32, 64);
        if (lane < 8) {
            const int bbL = ((lane & 1) << 2) | (lane & 2) | ((lane >> 2) & 1);
            const int o = jj * 8 + wv;
            y[(bbase + bbL) * NO + o] = v[0] * (1.0f / 64.0f);
        }
    }
}

// Reduce: spl_reg[j] = (sum_chunk part[chunk][j]) / 2048 / (t9 - t0 + 1e-5)
__global__ __launch_bounds__(256) void kan_reduce(
    const float* __restrict__ regpart, const float* __restrict__ grid,
    float* __restrict__ outreg)
{
    __shared__ float sR[4][64];
    const int t = threadIdx.x;
    const int qo = t & 63, gs = t >> 6;
    const int q = blockIdx.x * 64 + qo;
    float s = 0.0f;
#pragma unroll 16
    for (int g = gs * 64; g < gs * 64 + 64; ++g) s += regpart[g * NTOTAL + q];
    sR[gs][qo] = s;
    __syncthreads();
    if (t < 64) {
        const float tot = sR[0][qo] + sR[1][qo] + sR[2][qo] + sR[3][qo];
        const float norm = grid[q * 10 + 9] - grid[q * 10] + 1e-5f;
        outreg[q] = (tot * (1.0f / (float)BATCHN)) / norm;
    }
}

// Fallback (ws too small): round-3 standalone spl_reg kernel (known-good).
__global__ __launch_bounds__(256) void kan_reg_standalone(
    const float* __restrict__ x, const float* __restrict__ cb,
    const float* __restrict__ grid, float* __restrict__ outreg)
{
    __shared__ float sB2[6][256];
    __shared__ float sR[256];
    const int t = threadIdx.x;
    const int i = blockIdx.x;

    float tt[10];
#pragma unroll
    for (int m = 0; m < 10; ++m) tt[m] = grid[m];
    float inv1[9], inv2[8], inv3[7];
#pragma unroll
    for (int m = 0; m < 9; ++m) inv1[m] = 1.0f / (tt[m + 1] - tt[m]);
#pragma unroll
    for (int m = 0; m < 8; ++m) inv2[m] = 1.0f / (tt[m + 2] - tt[m]);
#pragma unroll
    for (int m = 0; m < 7; ++m) inv3[m] = 1.0f / (tt[m + 3] - tt[m]);

    const int o = t >> 2;
    const int q = t & 3;
    const int j = o * NI + i;
    const float c0 = cb[j * 6 + 0], c1 = cb[j * 6 + 1], c2 = cb[j * 6 + 2];
    const float c3 = cb[j * 6 + 3], c4 = cb[j * 6 + 4], c5 = cb[j * 6 + 5];

    float acc = 0.0f;
    for (int tile = 0; tile < 8; ++tile) {
        const float xv = x[(tile * 256 + t) * NI + i];
        float bo[6], sl;
        eval_basis6(xv, tt, inv1, inv2, inv3, bo, &sl);
        __syncthreads();
#pragma unroll
        for (int m = 0; m < 6; ++m) sB2[m][t] = bo[m];
        __syncthreads();
        for (int bi = 0; bi < 64; ++bi) {
            const int b = q * 64 + ((bi + q * 8) & 63);
            float s = c0 * sB2[0][b];
            s = fmaf(c1, sB2[1][b], s);
            s = fmaf(c2, sB2[2][b], s);
            s = fmaf(c3, sB2[3][b], s);
            s = fmaf(c4, sB2[4][b], s);
            s = fmaf(c5, sB2[5][b], s);
            acc += fabsf(s);
        }
    }
    sR[t] = acc;
    __syncthreads();
    if (t < 64) {
        const float s = sR[t * 4 + 0] + sR[t * 4 + 1] + sR[t * 4 + 2] + sR[t * 4 + 3];
        const int jj = t * NI + i;
        const float norm = grid[jj * 10 + 9] - grid[jj * 10] + 1e-5f;
        outreg[jj] = (s * (1.0f / (float)BATCHN)) / norm;
    }
}

extern "C" void kernel_launch(void* const* d_in, const int* in_sizes, int n_in,
                              void* d_out, int out_size, void* d_ws, size_t ws_size,
                              hipStream_t stream) {
    (void)in_sizes; (void)n_in; (void)out_size;
    const float* x    = (const float*)d_in[0];
    const float* cb   = (const float*)d_in[1];
    const float* cspl = (const float*)d_in[2];
    const float* cres = (const float*)d_in[3];
    const float* grid = (const float*)d_in[4];
    float* y      = (float*)d_out;
    float* outreg = y + BATCHN * NO;

    const size_t needed = (size_t)NCHUNK * NTOTAL * sizeof(float);   // 4 MiB
    if (ws_size >= needed) {
        float* part = (float*)d_ws;
        kan_main<<<NCHUNK, TPB, 0, stream>>>(x, cb, cspl, cres, grid, y, part, 1);
        kan_reduce<<<NTOTAL / 64, 256, 0, stream>>>(part, grid, outreg);
    } else {
        kan_main<<<NCHUNK, TPB, 0, stream>>>(x, cb, cspl, cres, grid, y,
                                             (float*)d_ws, 0);
        kan_reg_standalone<<<NI, 256, 0, stream>>>(x, cb, grid, outreg);
    }
}